// Round 6
// baseline (421.342 us; speedup 1.0000x reference)
//
#include <hip/hip_runtime.h>
#include <hip/hip_bf16.h>

#define BB 16
#define DDIM 256
#define TLEN 4096
#define KCODES 1024
#define NQ (BB*TLEN)   // 65536
#define MAXC 32
#define DELTA 4e-4f

#define FLT_MAX_C 3.402823466e+38f

using short8 = __attribute__((ext_vector_type(8))) short;
using f32x4  = __attribute__((ext_vector_type(4))) float;

// RNE fp32 -> bf16 (bit pattern), and back
__device__ __forceinline__ unsigned short f2bf(float x) {
  unsigned u = __float_as_uint(x);
  unsigned r = (u + 0x7fffu + ((u >> 16) & 1u)) >> 16;
  return (unsigned short)r;
}
__device__ __forceinline__ float bf2f(unsigned short h) {
  return __uint_as_float(((unsigned)h) << 16);
}

// ---------------------------------------------------------------------------
// numpy pairwise sum-of-squares over 256 elements (stride in elements).
// ---------------------------------------------------------------------------
__device__ __forceinline__ float np_sumsq_256(const float* p, int stride) {
  float th[2];
#pragma unroll
  for (int h = 0; h < 2; ++h) {
    const float* q = p + (size_t)h * 128 * (size_t)stride;
    float r[8];
#pragma unroll
    for (int j = 0; j < 8; ++j) {
      float v = q[(size_t)j * (size_t)stride];
      r[j] = __fmul_rn(v, v);
    }
    for (int i = 8; i < 128; i += 8) {
#pragma unroll
      for (int j = 0; j < 8; ++j) {
        float v = q[(size_t)(i + j) * (size_t)stride];
        r[j] = __fadd_rn(r[j], __fmul_rn(v, v));
      }
    }
    th[h] = __fadd_rn(__fadd_rn(__fadd_rn(r[0], r[1]), __fadd_rn(r[2], r[3])),
                      __fadd_rn(__fadd_rn(r[4], r[5]), __fadd_rn(r[6], r[7])));
  }
  return __fadd_rn(th[0], th[1]);
}

// ---------------------------------------------------------------------------
// k_prep: embT (for gather), e2 exact, bf16 hi/lo split of emb [k][d]
// ---------------------------------------------------------------------------
__global__ void k_prep(const float* __restrict__ emb, float* __restrict__ embT,
                       float* __restrict__ e2, short* __restrict__ ebh,
                       short* __restrict__ ebl) {
  const int k = blockIdx.x;
  const int d = threadIdx.x;
  __shared__ float row[DDIM];
  float v = emb[(size_t)k * DDIM + d];
  row[d] = v;
  embT[(size_t)d * KCODES + k] = v;
  unsigned short h = f2bf(v);
  ebh[(size_t)k * DDIM + d] = (short)h;
  ebl[(size_t)k * DDIM + d] = (short)f2bf(v - bf2f(h));
  __syncthreads();
  if (d == 0) e2[k] = np_sumsq_256(row, 1);
}

// ---------------------------------------------------------------------------
// k_zsplit: per 32-query tile — stage z [d][q] in LDS (coalesced), compute
// exact numpy-pairwise z2, write bf16 hi/lo of z transposed to [n][d].
// ---------------------------------------------------------------------------
__global__ __launch_bounds__(256)
void k_zsplit(const float* __restrict__ z, short* __restrict__ zbh,
              short* __restrict__ zbl, float* __restrict__ z2) {
  __shared__ float lds[DDIM * 33];  // [d][q], pad 33
  const int tid = threadIdx.x;
  const int n0 = blockIdx.x * 32;
  const int b = n0 >> 12;
  const int t0 = n0 & (TLEN - 1);
  const float* zp = z + (size_t)b * DDIM * TLEN + t0;

#pragma unroll
  for (int i = 0; i < 32; ++i) {
    int s = i * 256 + tid;  // < 8192
    int d = s >> 5, q = s & 31;
    lds[d * 33 + q] = zp[(size_t)d * TLEN + q];
  }
  __syncthreads();
  if (tid < 32) z2[n0 + tid] = np_sumsq_256(&lds[tid], 33);

#pragma unroll
  for (int i = 0; i < 4; ++i) {
    int flat = i * 256 + tid;           // < 1024
    int q = flat >> 5, dc = flat & 31;  // 32 consecutive lanes share q
    int d0 = dc * 8;
    short8 h, l;
#pragma unroll
    for (int j = 0; j < 8; ++j) {
      float v = lds[(d0 + j) * 33 + q];
      unsigned short hh = f2bf(v);
      h[j] = (short)hh;
      l[j] = (short)f2bf(v - bf2f(hh));
    }
    size_t o = (size_t)(n0 + q) * DDIM + d0;
    *(short8*)(zbh + o) = h;
    *(short8*)(zbl + o) = l;
  }
}

// ---------------------------------------------------------------------------
// k_z2 (fallback when workspace too small for zbh/zbl)
// ---------------------------------------------------------------------------
__global__ void k_z2(const float* __restrict__ z, float* __restrict__ z2) {
  const int n = blockIdx.x * 256 + threadIdx.x;
  const int b = n >> 12;
  const int t = n & (TLEN - 1);
  const float* p = z + (size_t)b * DDIM * TLEN + t;
  z2[n] = np_sumsq_256(p, TLEN);
}

// ---------------------------------------------------------------------------
// k_mdist v2: 1024 threads = 16 waves; block = 64 queries x 1024 codes.
// Wave w: qg=w>>3 (32 q), kb=(w&7)*128 (128 codes); mt=0..1, nt=0..7, ks=0..7.
// acc[2][8] f32x4 = 64 VGPR -> no spills. A/B = 16B global loads of bf16
// hi/lo (PRE=1) or in-loop build (PRE=0 fallback).
// Epilogue: DELTA candidate filter + exact fp32 recheck -> bit-exact argmin.
// ---------------------------------------------------------------------------
template <int PRE>
__global__ __launch_bounds__(1024)
void k_mdist(const float* __restrict__ z, const float* __restrict__ emb,
             const short* __restrict__ zbh, const short* __restrict__ zbl,
             const short* __restrict__ ebh, const short* __restrict__ ebl,
             const float* __restrict__ e2, const float* __restrict__ z2,
             int* __restrict__ idx, int* __restrict__ hist,
             double* __restrict__ lossp) {
  const int tid = threadIdx.x;
  const int lane = tid & 63;
  const int w = tid >> 6;   // 0..15
  const int g = lane >> 4;  // 0..3
  const int c = lane & 15;
  const int n0 = blockIdx.x * 64;
  const int qg = w >> 3;         // 0..1
  const int kb = (w & 7) * 128;  // code base
  const int nq0 = n0 + qg * 32;  // wave's first query (global n)
  const float* zbase = z + (size_t)(n0 >> 12) * DDIM * TLEN + (n0 & (TLEN - 1));

  f32x4 acc[2][8];
#pragma unroll
  for (int mt = 0; mt < 2; ++mt)
#pragma unroll
    for (int nt = 0; nt < 8; ++nt) {
      f32x4 zz = {0.f, 0.f, 0.f, 0.f};
      acc[mt][nt] = zz;
    }

  for (int ks = 0; ks < 8; ++ks) {
    short8 ah[2], al[2];
#pragma unroll
    for (int mt = 0; mt < 2; ++mt) {
      if (PRE) {
        const size_t ao = (size_t)(nq0 + mt * 16 + c) * DDIM + ks * 32 + g * 8;
        ah[mt] = *(const short8*)(zbh + ao);
        al[mt] = *(const short8*)(zbl + ao);
      } else {
        const int q = qg * 32 + mt * 16 + c;
        const int dbase = ks * 32 + g * 8;
        float av[8];
#pragma unroll
        for (int j = 0; j < 8; ++j)
          av[j] = zbase[(size_t)(dbase + j) * TLEN + q];
#pragma unroll
        for (int j = 0; j < 8; ++j) {
          unsigned short h = f2bf(av[j]);
          ah[mt][j] = (short)h;
          al[mt][j] = (short)f2bf(av[j] - bf2f(h));
        }
      }
    }
#pragma unroll
    for (int nt = 0; nt < 8; ++nt) {
      const size_t eo = (size_t)(kb + nt * 16 + c) * DDIM + ks * 32 + g * 8;
      short8 bh = *(const short8*)(ebh + eo);
      short8 bl = *(const short8*)(ebl + eo);
#pragma unroll
      for (int mt = 0; mt < 2; ++mt) {
        acc[mt][nt] = __builtin_amdgcn_mfma_f32_16x16x32_bf16(ah[mt], bh, acc[mt][nt], 0, 0, 0);
        acc[mt][nt] = __builtin_amdgcn_mfma_f32_16x16x32_bf16(al[mt], bh, acc[mt][nt], 0, 0, 0);
        acc[mt][nt] = __builtin_amdgcn_mfma_f32_16x16x32_bf16(ah[mt], bl, acc[mt][nt], 0, 0, 0);
      }
    }
  }

  // ---- epilogue ----
  __shared__ float sm[16][32];
  __shared__ float qmin[64];
  __shared__ int cnt[64];
  __shared__ int ovf[64];
  __shared__ int cand[64][MAXC];
  __shared__ float bd[64][16];
  __shared__ int bk[64][16];

  float e2c[8];
#pragma unroll
  for (int nt = 0; nt < 8; ++nt) e2c[nt] = e2[kb + nt * 16 + c];

  float smin[2][4];
#pragma unroll
  for (int mt = 0; mt < 2; ++mt)
#pragma unroll
    for (int r = 0; r < 4; ++r) {
      float m = FLT_MAX_C;
#pragma unroll
      for (int nt = 0; nt < 8; ++nt)
        m = fminf(m, e2c[nt] - 2.0f * acc[mt][nt][r]);
      smin[mt][r] = m;
    }
#pragma unroll
  for (int mt = 0; mt < 2; ++mt)
#pragma unroll
    for (int r = 0; r < 4; ++r) {
#pragma unroll
      for (int m = 1; m < 16; m <<= 1)
        smin[mt][r] = fminf(smin[mt][r], __shfl_xor(smin[mt][r], m, 64));
    }
  if (c == 0) {
#pragma unroll
    for (int mt = 0; mt < 2; ++mt)
#pragma unroll
      for (int r = 0; r < 4; ++r)
        sm[w][mt * 16 + g * 4 + r] = smin[mt][r];
  }
  if (tid < 64) { cnt[tid] = 0; ovf[tid] = 0; }
  __syncthreads();
  if (tid < 64) {
    const int qq = tid >> 5, j = tid & 31;
    float m = sm[qq * 8][j];
#pragma unroll
    for (int wv = 1; wv < 8; ++wv) m = fminf(m, sm[qq * 8 + wv][j]);
    qmin[tid] = m;
  }
  __syncthreads();

  // candidate collection
#pragma unroll
  for (int mt = 0; mt < 2; ++mt)
#pragma unroll
    for (int r = 0; r < 4; ++r) {
      const int ql = qg * 32 + mt * 16 + g * 4 + r;
      const float lim = qmin[ql] + DELTA;
#pragma unroll
      for (int nt = 0; nt < 8; ++nt) {
        float s = e2c[nt] - 2.0f * acc[mt][nt][r];
        if (s <= lim) {
          int p = atomicAdd(&cnt[ql], 1);
          if (p < MAXC) cand[ql][p] = kb + nt * 16 + c;
          else ovf[ql] = 1;
        }
      }
    }
  __syncthreads();

  // exact recheck (reference fp32 chain), 16 slots per query
  {
    const int q = tid & 63;
    const int slot = tid >> 6;
    const int n = n0 + q;
    const float z2q = z2[n];
    const float* zq = zbase + q;
    float bestd = FLT_MAX_C;
    int besti = (1 << 30);
    const bool all = (ovf[q] != 0) || (cnt[q] > MAXC);
    const int count = all ? KCODES : cnt[q];
    for (int ci = slot; ci < count; ci += 16) {
      const int k = all ? ci : cand[q][ci];
      const float* ek = emb + (size_t)k * DDIM;
      float a0 = 0.f;
      for (int d = 0; d < DDIM; ++d)
        a0 = __fmaf_rn(zq[(size_t)d * TLEN], ek[d], a0);
      float dist = __fsub_rn(__fadd_rn(z2q, e2[k]), __fmul_rn(2.0f, a0));
      if (dist < bestd || (dist == bestd && k < besti)) { bestd = dist; besti = k; }
    }
    bd[q][slot] = bestd;
    bk[q][slot] = besti;
  }
  __syncthreads();

  if (tid < 64) {
    float B = bd[tid][0];
    int K = bk[tid][0];
#pragma unroll
    for (int s = 1; s < 16; ++s) {
      float d2 = bd[tid][s];
      int k2 = bk[tid][s];
      if (d2 < B || (d2 == B && k2 < K)) { B = d2; K = k2; }
    }
    const int n = n0 + tid;
    idx[n] = K;
    atomicAdd(&hist[K], 1);
    double ls = (double)B;
#pragma unroll
    for (int m = 1; m < 64; m <<= 1) ls += __shfl_xor(ls, m, 64);
    if (tid == 0) lossp[blockIdx.x] = ls;
  }
}

// ---------------------------------------------------------------------------
// k_idxout: indices as FLOAT32
// ---------------------------------------------------------------------------
__global__ void k_idxout(const int* __restrict__ idx,
                         float* __restrict__ oidx) {
  int n = blockIdx.x * 256 + threadIdx.x;
  oidx[n] = (float)(idx[n] & (KCODES - 1));
}

// ---------------------------------------------------------------------------
// k_gather: out[b,d,t] = emb[idx[b,t], d]; one block per (b,d)
// ---------------------------------------------------------------------------
__global__ void k_gather(const float* __restrict__ embT,
                         const int* __restrict__ idx,
                         float* __restrict__ out) {
  __shared__ float er[KCODES];
  const int blk = blockIdx.x;  // b*D + d
  const int bq = blk >> 8;
  const int d = blk & 255;
  const int tid = threadIdx.x;
  *((float4*)&er[tid * 4]) =
      *((const float4*)(embT + (size_t)d * KCODES + tid * 4));
  __syncthreads();
  const int* ip = idx + (size_t)bq * TLEN;
  float* op = out + (size_t)blk * TLEN;
#pragma unroll
  for (int c = 0; c < 16; ++c) {
    int t = c * 256 + tid;
    int kk = ip[t] & (KCODES - 1);
    op[t] = er[kk];
  }
}

// ---------------------------------------------------------------------------
// k_final: loss and perplexity (deterministic fixed-tree reductions)
// ---------------------------------------------------------------------------
__global__ void k_final(const int* __restrict__ hist,
                        const double* __restrict__ lossp,
                        float* __restrict__ out2) {
  const int tid = threadIdx.x;  // 256
  double ls = 0.0;
  for (int i = 0; i < 4; ++i) ls += lossp[tid * 4 + i];  // 1024 partials
  float es = 0.f;
  for (int i = tid; i < KCODES; i += 256) {
    float p = (float)hist[i] / 65536.0f;
    es += p * logf(p + 1e-10f);
  }
#pragma unroll
  for (int m = 1; m < 64; m <<= 1) {
    ls += __shfl_xor(ls, m, 64);
    es += __shfl_xor(es, m, 64);
  }
  __shared__ double lw[4];
  __shared__ float ew[4];
  if ((tid & 63) == 0) { lw[tid >> 6] = ls; ew[tid >> 6] = es; }
  __syncthreads();
  if (tid == 0) {
    double lt = lw[0] + lw[1] + lw[2] + lw[3];
    float et = ew[0] + ew[1] + ew[2] + ew[3];
    float loss = 0.25f * (float)(lt / (double)((long long)NQ * DDIM));
    float perp = expf(-et);
    out2[0] = loss;
    out2[1] = perp;
  }
}

// ---------------------------------------------------------------------------
// workspace layout (bytes):
//   embT  : 0        .. 1048576   (D*K floats)
//   e2    : 1048576  .. 1052672   (K floats)
//   z2    : 1052672  .. 1314816   (N floats)
//   idx   : 1314816  .. 1576960   (N ints)
//   hist  : 1576960  .. 1581056   (K ints)        <- memset each launch
//   lossp : 1581056  .. 1589248   (1024 doubles)  <- fully written
//   ebh   : 1589248  .. 2113536   (K*D bf16 hi)
//   ebl   : 2113536  .. 2637824   (K*D bf16 lo)
//   zbh   : 2637824  .. 36192256  (N*D bf16 hi)   <- only if ws_size allows
//   zbl   : 36192256 .. 69746688  (N*D bf16 lo)
// ---------------------------------------------------------------------------
extern "C" void kernel_launch(void* const* d_in, const int* in_sizes, int n_in,
                              void* d_out, int out_size, void* d_ws, size_t ws_size,
                              hipStream_t stream) {
  const float* z = (const float*)d_in[0];
  const float* emb = (const float*)d_in[1];
  float* out = (float*)d_out;

  char* ws = (char*)d_ws;
  float* embT = (float*)(ws);
  float* e2 = (float*)(ws + 1048576);
  float* z2 = (float*)(ws + 1052672);
  int* idx = (int*)(ws + 1314816);
  int* hist = (int*)(ws + 1576960);
  double* lossp = (double*)(ws + 1581056);
  short* ebh = (short*)(ws + 1589248);
  short* ebl = (short*)(ws + 2113536);
  short* zbh = (short*)(ws + 2637824);
  short* zbl = (short*)(ws + 36192256);

  const bool pre = (ws_size >= 69746688ull);

  float* oidx = out + ((size_t)out_size - 2 - NQ);
  float* out2 = out + ((size_t)out_size - 2);

  hipMemsetAsync(hist, 0, KCODES * sizeof(int), stream);

  k_prep<<<KCODES, 256, 0, stream>>>(emb, embT, e2, ebh, ebl);
  if (pre) {
    k_zsplit<<<NQ / 32, 256, 0, stream>>>(z, zbh, zbl, z2);
    k_mdist<1><<<NQ / 64, 1024, 0, stream>>>(z, emb, zbh, zbl, ebh, ebl, e2,
                                             z2, idx, hist, lossp);
  } else {
    k_z2<<<NQ / 256, 256, 0, stream>>>(z, z2);
    k_mdist<0><<<NQ / 64, 1024, 0, stream>>>(z, emb, zbh, zbl, ebh, ebl, e2,
                                             z2, idx, hist, lossp);
  }
  k_idxout<<<NQ / 256, 256, 0, stream>>>(idx, oidx);
  k_gather<<<BB * DDIM, 256, 0, stream>>>(embT, idx, out);
  k_final<<<1, 256, 0, stream>>>(hist, lossp, out2);
}

// Round 7
// 357.256 us; speedup vs baseline: 1.1794x; 1.1794x over previous
//
#include <hip/hip_runtime.h>
#include <hip/hip_bf16.h>

#define BB 16
#define DDIM 256
#define TLEN 4096
#define KCODES 1024
#define NQ (BB*TLEN)   // 65536
#define QB 32          // queries per k_mdist block
#define MAXC 32
#define DELTA 4e-4f

#define FLT_MAX_C 3.402823466e+38f

using short8 = __attribute__((ext_vector_type(8))) short;
using f32x4  = __attribute__((ext_vector_type(4))) float;

// RNE fp32 -> bf16 (bit pattern), and back
__device__ __forceinline__ unsigned short f2bf(float x) {
  unsigned u = __float_as_uint(x);
  unsigned r = (u + 0x7fffu + ((u >> 16) & 1u)) >> 16;
  return (unsigned short)r;
}
__device__ __forceinline__ float bf2f(unsigned short h) {
  return __uint_as_float(((unsigned)h) << 16);
}

// ---------------------------------------------------------------------------
// numpy pairwise sum-of-squares over 256 elements (stride in elements).
// ---------------------------------------------------------------------------
__device__ __forceinline__ float np_sumsq_256(const float* p, int stride) {
  float th[2];
#pragma unroll
  for (int h = 0; h < 2; ++h) {
    const float* q = p + (size_t)h * 128 * (size_t)stride;
    float r[8];
#pragma unroll
    for (int j = 0; j < 8; ++j) {
      float v = q[(size_t)j * (size_t)stride];
      r[j] = __fmul_rn(v, v);
    }
    for (int i = 8; i < 128; i += 8) {
#pragma unroll
      for (int j = 0; j < 8; ++j) {
        float v = q[(size_t)(i + j) * (size_t)stride];
        r[j] = __fadd_rn(r[j], __fmul_rn(v, v));
      }
    }
    th[h] = __fadd_rn(__fadd_rn(__fadd_rn(r[0], r[1]), __fadd_rn(r[2], r[3])),
                      __fadd_rn(__fadd_rn(r[4], r[5]), __fadd_rn(r[6], r[7])));
  }
  return __fadd_rn(th[0], th[1]);
}

// ---------------------------------------------------------------------------
// k_prep: embT (for gather), e2 exact, bf16 hi/lo split of emb [k][d]
// ---------------------------------------------------------------------------
__global__ void k_prep(const float* __restrict__ emb, float* __restrict__ embT,
                       float* __restrict__ e2, short* __restrict__ ebh,
                       short* __restrict__ ebl) {
  const int k = blockIdx.x;
  const int d = threadIdx.x;
  __shared__ float row[DDIM];
  float v = emb[(size_t)k * DDIM + d];
  row[d] = v;
  embT[(size_t)d * KCODES + k] = v;
  unsigned short h = f2bf(v);
  ebh[(size_t)k * DDIM + d] = (short)h;
  ebl[(size_t)k * DDIM + d] = (short)f2bf(v - bf2f(h));
  __syncthreads();
  if (d == 0) e2[k] = np_sumsq_256(row, 1);
}

// ---------------------------------------------------------------------------
// k_mdist v3: 512 threads = 8 waves; block = 32 queries x 1024 codes.
// Wave w owns codes [w*128,(w+1)*128). A-fragments (bf16 hi/lo of z) are
// cooperatively built ONCE into LDS; the ks loop is pure
// {2x ds_read_b128 (A), 16x global 16B (B, L2-resident), 48 MFMA}.
// acc[2][8] f32x4 = 64 VGPR; launch_bounds(512,1) -> cap 256 -> no spills.
// Epilogue: approx score min + DELTA candidate filter + exact fp32 recheck
// (reference rounding chain, z from LDS) -> bit-exact first-occurrence argmin.
// LDS: zf 32KB + ab 32KB (epilogue arrays alias ab after the MFMA loop).
// ---------------------------------------------------------------------------
__global__ __launch_bounds__(512, 1)
void k_mdist(const float* __restrict__ z, const float* __restrict__ emb,
             const short* __restrict__ ebh, const short* __restrict__ ebl,
             const float* __restrict__ e2, int* __restrict__ idx,
             int* __restrict__ hist, double* __restrict__ lossp) {
  __shared__ __align__(16) char sbuf[65536];
  float*  zf  = (float*)sbuf;                      // [256][32] exact z tile
  short8* abh = (short8*)(sbuf + 32768);           // [8ks][2mt][64lane]
  short8* abl = (short8*)(sbuf + 49152);
  // epilogue aliases into the ab region (dead after MFMA loop):
  float* z2s  = (float*)(sbuf + 32768);            // [32]
  float* sm   = (float*)(sbuf + 32768 + 128);      // [8][32]
  float* qmin = (float*)(sbuf + 32768 + 1152);     // [32]
  int*   cnt  = (int*)(sbuf + 32768 + 1280);       // [32]
  int*   ovf  = (int*)(sbuf + 32768 + 1408);       // [32]
  int*   cand = (int*)(sbuf + 32768 + 1536);       // [32][MAXC]
  float* bd   = (float*)(sbuf + 32768 + 5632);     // [32][16]
  int*   bk   = (int*)(sbuf + 32768 + 7680);       // [32][16]

  const int tid = threadIdx.x;
  const int lane = tid & 63;
  const int w = tid >> 6;   // 0..7
  const int g = lane >> 4;  // 0..3
  const int c = lane & 15;
  const int n0 = blockIdx.x * QB;
  const int kb = w * 128;
  const float* zp = z + (size_t)(n0 >> 12) * DDIM * TLEN + (n0 & (TLEN - 1));

  // ---- stage zf[d][q] (exact fp32), coalesced float4 ----
#pragma unroll
  for (int i = 0; i < 4; ++i) {
    int s4 = i * 512 + tid;            // 2048 float4 slots
    int d = s4 >> 3, q4 = (s4 & 7) * 4;
    *(float4*)&zf[d * QB + q4] = *(const float4*)(zp + (size_t)d * TLEN + q4);
  }
  __syncthreads();

  // ---- cooperative A-fragment build (once per block) ----
#pragma unroll
  for (int i = 0; i < 2; ++i) {
    int s = i * 512 + tid;             // 1024 slots: ks(8) x mt(2) x lane(64)
    int ks = s >> 7, mt = (s >> 6) & 1, ln = s & 63;
    int q = mt * 16 + (ln & 15);
    int d0 = ks * 32 + (ln >> 4) * 8;
    short8 h, l;
#pragma unroll
    for (int j = 0; j < 8; ++j) {
      float v = zf[(d0 + j) * QB + q];
      unsigned short hh = f2bf(v);
      h[j] = (short)hh;
      l[j] = (short)f2bf(v - bf2f(hh));
    }
    abh[s] = h;
    abl[s] = l;
  }
  __syncthreads();

  // ---- MFMA main loop ----
  f32x4 acc[2][8];
#pragma unroll
  for (int mt = 0; mt < 2; ++mt)
#pragma unroll
    for (int nt = 0; nt < 8; ++nt) {
      f32x4 zz = {0.f, 0.f, 0.f, 0.f};
      acc[mt][nt] = zz;
    }

  for (int ks = 0; ks < 8; ++ks) {
    short8 ah0 = abh[ks * 128 + lane];
    short8 al0 = abl[ks * 128 + lane];
    short8 ah1 = abh[ks * 128 + 64 + lane];
    short8 al1 = abl[ks * 128 + 64 + lane];
#pragma unroll
    for (int nt = 0; nt < 8; ++nt) {
      const size_t eo = (size_t)(kb + nt * 16 + c) * DDIM + ks * 32 + g * 8;
      short8 bh = *(const short8*)(ebh + eo);
      short8 bl = *(const short8*)(ebl + eo);
      acc[0][nt] = __builtin_amdgcn_mfma_f32_16x16x32_bf16(ah0, bh, acc[0][nt], 0, 0, 0);
      acc[0][nt] = __builtin_amdgcn_mfma_f32_16x16x32_bf16(al0, bh, acc[0][nt], 0, 0, 0);
      acc[0][nt] = __builtin_amdgcn_mfma_f32_16x16x32_bf16(ah0, bl, acc[0][nt], 0, 0, 0);
      acc[1][nt] = __builtin_amdgcn_mfma_f32_16x16x32_bf16(ah1, bh, acc[1][nt], 0, 0, 0);
      acc[1][nt] = __builtin_amdgcn_mfma_f32_16x16x32_bf16(al1, bh, acc[1][nt], 0, 0, 0);
      acc[1][nt] = __builtin_amdgcn_mfma_f32_16x16x32_bf16(ah1, bl, acc[1][nt], 0, 0, 0);
    }
  }
  __syncthreads();  // ab reads done; aliases become writable

  // ---- z2 (exact pairwise, from LDS column) + epilogue init ----
  if (tid < QB) {
    z2s[tid] = np_sumsq_256(&zf[tid], QB);
    cnt[tid] = 0;
    ovf[tid] = 0;
  }

  float e2c[8];
#pragma unroll
  for (int nt = 0; nt < 8; ++nt) e2c[nt] = e2[kb + nt * 16 + c];

  float smin[2][4];
#pragma unroll
  for (int mt = 0; mt < 2; ++mt)
#pragma unroll
    for (int r = 0; r < 4; ++r) {
      float m = FLT_MAX_C;
#pragma unroll
      for (int nt = 0; nt < 8; ++nt)
        m = fminf(m, e2c[nt] - 2.0f * acc[mt][nt][r]);
      smin[mt][r] = m;
    }
#pragma unroll
  for (int mt = 0; mt < 2; ++mt)
#pragma unroll
    for (int r = 0; r < 4; ++r) {
#pragma unroll
      for (int m = 1; m < 16; m <<= 1)
        smin[mt][r] = fminf(smin[mt][r], __shfl_xor(smin[mt][r], m, 64));
    }
  if (c == 0) {
#pragma unroll
    for (int mt = 0; mt < 2; ++mt)
#pragma unroll
      for (int r = 0; r < 4; ++r)
        sm[w * QB + mt * 16 + g * 4 + r] = smin[mt][r];
  }
  __syncthreads();
  if (tid < QB) {
    float m = sm[tid];
#pragma unroll
    for (int wv = 1; wv < 8; ++wv) m = fminf(m, sm[wv * QB + tid]);
    qmin[tid] = m;
  }
  __syncthreads();

  // ---- candidate collection ----
#pragma unroll
  for (int mt = 0; mt < 2; ++mt)
#pragma unroll
    for (int r = 0; r < 4; ++r) {
      const int ql = mt * 16 + g * 4 + r;
      const float lim = qmin[ql] + DELTA;
#pragma unroll
      for (int nt = 0; nt < 8; ++nt) {
        float s = e2c[nt] - 2.0f * acc[mt][nt][r];
        if (s <= lim) {
          int p = atomicAdd(&cnt[ql], 1);
          if (p < MAXC) cand[ql * MAXC + p] = kb + nt * 16 + c;
          else ovf[ql] = 1;
        }
      }
    }
  __syncthreads();

  // ---- exact recheck (reference fp32 chain; z from LDS), 16 slots/query ----
  {
    const int q = tid & 31;
    const int slot = tid >> 5;
    const float z2q = z2s[q];
    float bestd = FLT_MAX_C;
    int besti = (1 << 30);
    const bool all = (ovf[q] != 0) || (cnt[q] > MAXC);
    const int count = all ? KCODES : cnt[q];
    for (int ci = slot; ci < count; ci += 16) {
      const int k = all ? ci : cand[q * MAXC + ci];
      const float4* ek = (const float4*)(emb + (size_t)k * DDIM);
      float a0 = 0.f;
      for (int dd = 0; dd < 64; ++dd) {
        float4 e4 = ek[dd];
        a0 = __fmaf_rn(zf[(dd * 4 + 0) * QB + q], e4.x, a0);
        a0 = __fmaf_rn(zf[(dd * 4 + 1) * QB + q], e4.y, a0);
        a0 = __fmaf_rn(zf[(dd * 4 + 2) * QB + q], e4.z, a0);
        a0 = __fmaf_rn(zf[(dd * 4 + 3) * QB + q], e4.w, a0);
      }
      float dist = __fsub_rn(__fadd_rn(z2q, e2[k]), __fmul_rn(2.0f, a0));
      if (dist < bestd || (dist == bestd && k < besti)) { bestd = dist; besti = k; }
    }
    bd[q * 16 + slot] = bestd;
    bk[q * 16 + slot] = besti;
  }
  __syncthreads();

  if (tid < QB) {
    float B = bd[tid * 16 + 0];
    int K = bk[tid * 16 + 0];
#pragma unroll
    for (int s = 1; s < 16; ++s) {
      float d2 = bd[tid * 16 + s];
      int k2 = bk[tid * 16 + s];
      if (d2 < B || (d2 == B && k2 < K)) { B = d2; K = k2; }
    }
    idx[n0 + tid] = K;
    atomicAdd(&hist[K], 1);
    double ls = (double)B;
#pragma unroll
    for (int m = 1; m < 32; m <<= 1) ls += __shfl_xor(ls, m, 64);
    if (tid == 0) lossp[blockIdx.x] = ls;
  }
}

// ---------------------------------------------------------------------------
// k_idxout: indices as FLOAT32
// ---------------------------------------------------------------------------
__global__ void k_idxout(const int* __restrict__ idx,
                         float* __restrict__ oidx) {
  int n = blockIdx.x * 256 + threadIdx.x;
  oidx[n] = (float)(idx[n] & (KCODES - 1));
}

// ---------------------------------------------------------------------------
// k_gather: out[b,d,t] = emb[idx[b,t], d]; one block per (b,d)
// ---------------------------------------------------------------------------
__global__ void k_gather(const float* __restrict__ embT,
                         const int* __restrict__ idx,
                         float* __restrict__ out) {
  __shared__ float er[KCODES];
  const int blk = blockIdx.x;  // b*D + d
  const int bq = blk >> 8;
  const int d = blk & 255;
  const int tid = threadIdx.x;
  *((float4*)&er[tid * 4]) =
      *((const float4*)(embT + (size_t)d * KCODES + tid * 4));
  __syncthreads();
  const int* ip = idx + (size_t)bq * TLEN;
  float* op = out + (size_t)blk * TLEN;
#pragma unroll
  for (int c = 0; c < 16; ++c) {
    int t = c * 256 + tid;
    int kk = ip[t] & (KCODES - 1);
    op[t] = er[kk];
  }
}

// ---------------------------------------------------------------------------
// k_final: loss and perplexity (deterministic fixed-tree reductions)
// lossp: 2048 per-block partials.
// ---------------------------------------------------------------------------
__global__ void k_final(const int* __restrict__ hist,
                        const double* __restrict__ lossp,
                        float* __restrict__ out2) {
  const int tid = threadIdx.x;  // 256
  double ls = 0.0;
  for (int i = 0; i < 8; ++i) ls += lossp[tid * 8 + i];
  float es = 0.f;
  for (int i = tid; i < KCODES; i += 256) {
    float p = (float)hist[i] / 65536.0f;
    es += p * logf(p + 1e-10f);
  }
#pragma unroll
  for (int m = 1; m < 64; m <<= 1) {
    ls += __shfl_xor(ls, m, 64);
    es += __shfl_xor(es, m, 64);
  }
  __shared__ double lw[4];
  __shared__ float ew[4];
  if ((tid & 63) == 0) { lw[tid >> 6] = ls; ew[tid >> 6] = es; }
  __syncthreads();
  if (tid == 0) {
    double lt = lw[0] + lw[1] + lw[2] + lw[3];
    float et = ew[0] + ew[1] + ew[2] + ew[3];
    float loss = 0.25f * (float)(lt / (double)((long long)NQ * DDIM));
    float perp = expf(-et);
    out2[0] = loss;
    out2[1] = perp;
  }
}

// ---------------------------------------------------------------------------
// workspace layout (bytes):
//   embT  : 0        .. 1048576   (D*K floats)
//   e2    : 1048576  .. 1052672   (K floats)
//   idx   : 1052672  .. 1314816   (N ints)
//   hist  : 1314816  .. 1318912   (K ints)        <- memset each launch
//   lossp : 1318912  .. 1335296   (2048 doubles)  <- fully written
//   ebh   : 1335296  .. 1859584   (K*D bf16 hi)
//   ebl   : 1859584  .. 2383872   (K*D bf16 lo)
// total ~2.4 MB
// ---------------------------------------------------------------------------
extern "C" void kernel_launch(void* const* d_in, const int* in_sizes, int n_in,
                              void* d_out, int out_size, void* d_ws, size_t ws_size,
                              hipStream_t stream) {
  const float* z = (const float*)d_in[0];
  const float* emb = (const float*)d_in[1];
  float* out = (float*)d_out;

  char* ws = (char*)d_ws;
  float* embT = (float*)(ws);
  float* e2 = (float*)(ws + 1048576);
  int* idx = (int*)(ws + 1052672);
  int* hist = (int*)(ws + 1314816);
  double* lossp = (double*)(ws + 1318912);
  short* ebh = (short*)(ws + 1335296);
  short* ebl = (short*)(ws + 1859584);

  float* oidx = out + ((size_t)out_size - 2 - NQ);
  float* out2 = out + ((size_t)out_size - 2);

  hipMemsetAsync(hist, 0, KCODES * sizeof(int), stream);

  k_prep<<<KCODES, 256, 0, stream>>>(emb, embT, e2, ebh, ebl);
  k_mdist<<<NQ / QB, 512, 0, stream>>>(z, emb, ebh, ebl, e2, idx, hist, lossp);
  k_idxout<<<NQ / 256, 256, 0, stream>>>(idx, oidx);
  k_gather<<<BB * DDIM, 256, 0, stream>>>(embT, idx, out);
  k_final<<<1, 256, 0, stream>>>(hist, lossp, out2);
}

// Round 8
// 228.328 us; speedup vs baseline: 1.8453x; 1.5647x over previous
//
#include <hip/hip_runtime.h>
#include <hip/hip_bf16.h>

#define BB 16
#define DDIM 256
#define TLEN 4096
#define KCODES 1024
#define NQ (BB*TLEN)   // 65536
#define QB 64          // queries per k_mdist block
#define MAXC 32
#define DELTA 4e-4f

#define FLT_MAX_C 3.402823466e+38f

using short8 = __attribute__((ext_vector_type(8))) short;
using f32x4  = __attribute__((ext_vector_type(4))) float;

// RNE fp32 -> bf16 (bit pattern), and back
__device__ __forceinline__ unsigned short f2bf(float x) {
  unsigned u = __float_as_uint(x);
  unsigned r = (u + 0x7fffu + ((u >> 16) & 1u)) >> 16;
  return (unsigned short)r;
}
__device__ __forceinline__ float bf2f(unsigned short h) {
  return __uint_as_float(((unsigned)h) << 16);
}

// ---------------------------------------------------------------------------
// numpy pairwise sum-of-squares over 256 elements (stride in elements).
// ---------------------------------------------------------------------------
__device__ __forceinline__ float np_sumsq_256(const float* p, int stride) {
  float th[2];
#pragma unroll
  for (int h = 0; h < 2; ++h) {
    const float* q = p + (size_t)h * 128 * (size_t)stride;
    float r[8];
#pragma unroll
    for (int j = 0; j < 8; ++j) {
      float v = q[(size_t)j * (size_t)stride];
      r[j] = __fmul_rn(v, v);
    }
    for (int i = 8; i < 128; i += 8) {
#pragma unroll
      for (int j = 0; j < 8; ++j) {
        float v = q[(size_t)(i + j) * (size_t)stride];
        r[j] = __fadd_rn(r[j], __fmul_rn(v, v));
      }
    }
    th[h] = __fadd_rn(__fadd_rn(__fadd_rn(r[0], r[1]), __fadd_rn(r[2], r[3])),
                      __fadd_rn(__fadd_rn(r[4], r[5]), __fadd_rn(r[6], r[7])));
  }
  return __fadd_rn(th[0], th[1]);
}

// ---------------------------------------------------------------------------
// k_prep: embT (for gather), e2 exact, bf16 hi/lo split of emb [k][d]
// ---------------------------------------------------------------------------
__global__ void k_prep(const float* __restrict__ emb, float* __restrict__ embT,
                       float* __restrict__ e2, short* __restrict__ ebh,
                       short* __restrict__ ebl) {
  const int k = blockIdx.x;
  const int d = threadIdx.x;
  __shared__ float row[DDIM];
  float v = emb[(size_t)k * DDIM + d];
  row[d] = v;
  embT[(size_t)d * KCODES + k] = v;
  unsigned short h = f2bf(v);
  ebh[(size_t)k * DDIM + d] = (short)h;
  ebl[(size_t)k * DDIM + d] = (short)f2bf(v - bf2f(h));
  __syncthreads();
  if (d == 0) e2[k] = np_sumsq_256(row, 1);
}

// ---------------------------------------------------------------------------
// k_mdist v4: 512 threads = 8 waves; block = 64 queries x 1024 codes.
// Wave w owns codes [w*128,(w+1)*128) and ALL 64 queries (mt=0..3).
// Each B-fragment pair (32B from L2) feeds 12 MFMAs; B loads rotate through
// a 1-deep register prefetch so one load-pair is always in flight behind a
// 12-MFMA burst. acc[4][8] f32x4 = 128 VGPR, launch_bounds(512,2) -> cap 256.
// LDS (dynamic 128KB): zf fp32 [256][64] (64KB) + prebuilt A-frags bf16
// hi/lo [8ks][4mt][64lane] (64KB, epilogue arrays alias into it).
// Epilogue: approx score min + DELTA candidate filter + exact fp32 recheck
// (reference rounding chain, z from LDS) -> bit-exact first-occurrence argmin.
// ---------------------------------------------------------------------------
__global__ __launch_bounds__(512, 2)
void k_mdist(const float* __restrict__ z, const float* __restrict__ emb,
             const short* __restrict__ ebh, const short* __restrict__ ebl,
             const float* __restrict__ e2, int* __restrict__ idx,
             int* __restrict__ hist, double* __restrict__ lossp) {
  extern __shared__ __align__(16) char sbuf[];   // 131072 bytes
  float*  zf  = (float*)sbuf;                    // [256][64] exact z tile
  short8* abh = (short8*)(sbuf + 65536);         // [8ks][4mt][64lane]
  short8* abl = (short8*)(sbuf + 98304);
  // epilogue aliases into the abh region (dead after MFMA loop):
  float* z2s  = (float*)(sbuf + 65536);          // [64]
  float* sm   = (float*)(sbuf + 65536 + 256);    // [8][64]
  float* qmin = (float*)(sbuf + 65536 + 2304);   // [64]
  int*   cnt  = (int*)(sbuf + 65536 + 2560);     // [64]
  int*   ovf  = (int*)(sbuf + 65536 + 2816);     // [64]
  int*   cand = (int*)(sbuf + 65536 + 3072);     // [64][MAXC]
  float* bd   = (float*)(sbuf + 65536 + 11264);  // [64][8]
  int*   bk   = (int*)(sbuf + 65536 + 13312);    // [64][8]

  const int tid = threadIdx.x;
  const int lane = tid & 63;
  const int w = tid >> 6;   // 0..7
  const int g = lane >> 4;  // 0..3
  const int c = lane & 15;
  const int n0 = blockIdx.x * QB;
  const int kb = w * 128;
  const float* zp = z + (size_t)(n0 >> 12) * DDIM * TLEN + (n0 & (TLEN - 1));

  // ---- stage zf[d][q] (exact fp32), coalesced float4 ----
#pragma unroll
  for (int i = 0; i < 8; ++i) {
    int s4 = i * 512 + tid;            // 4096 float4 slots
    int d = s4 >> 4, q4 = (s4 & 15) * 4;
    *(float4*)&zf[d * QB + q4] = *(const float4*)(zp + (size_t)d * TLEN + q4);
  }
  __syncthreads();

  // ---- cooperative A-fragment build (once per block) ----
#pragma unroll
  for (int i = 0; i < 4; ++i) {
    int s = i * 512 + tid;             // 2048 slots: ks(8) x mt(4) x lane(64)
    int ks = s >> 8, mt = (s >> 6) & 3, ln = s & 63;
    int q = mt * 16 + (ln & 15);
    int d0 = ks * 32 + (ln >> 4) * 8;
    short8 h, l;
#pragma unroll
    for (int j = 0; j < 8; ++j) {
      float v = zf[(d0 + j) * QB + q];
      unsigned short hh = f2bf(v);
      h[j] = (short)hh;
      l[j] = (short)f2bf(v - bf2f(hh));
    }
    abh[s] = h;
    abl[s] = l;
  }
  __syncthreads();

  // ---- MFMA main loop ----
  f32x4 acc[4][8];
#pragma unroll
  for (int mt = 0; mt < 4; ++mt)
#pragma unroll
    for (int nt = 0; nt < 8; ++nt) {
      f32x4 zz = {0.f, 0.f, 0.f, 0.f};
      acc[mt][nt] = zz;
    }

  const size_t lbase = (size_t)(kb + c) * DDIM + g * 8;
  const short* ebp_h = ebh + lbase;
  const short* ebp_l = ebl + lbase;
  short8 pbh = *(const short8*)(ebp_h);
  short8 pbl = *(const short8*)(ebp_l);

  for (int ks = 0; ks < 8; ++ks) {
    short8 ah[4], al[4];
#pragma unroll
    for (int mt = 0; mt < 4; ++mt) {
      ah[mt] = abh[ks * 256 + mt * 64 + lane];
      al[mt] = abl[ks * 256 + mt * 64 + lane];
    }
#pragma unroll
    for (int nt = 0; nt < 8; ++nt) {
      short8 bh = pbh, bl = pbl;
      if (!(ks == 7 && nt == 7)) {
        int nm = ks * 8 + nt + 1;
        size_t off = (size_t)(nm & 7) * (16 * DDIM) + (size_t)(nm >> 3) * 32;
        pbh = *(const short8*)(ebp_h + off);
        pbl = *(const short8*)(ebp_l + off);
      }
#pragma unroll
      for (int mt = 0; mt < 4; ++mt) {
        acc[mt][nt] = __builtin_amdgcn_mfma_f32_16x16x32_bf16(ah[mt], bh, acc[mt][nt], 0, 0, 0);
        acc[mt][nt] = __builtin_amdgcn_mfma_f32_16x16x32_bf16(al[mt], bh, acc[mt][nt], 0, 0, 0);
        acc[mt][nt] = __builtin_amdgcn_mfma_f32_16x16x32_bf16(ah[mt], bl, acc[mt][nt], 0, 0, 0);
      }
    }
  }
  __syncthreads();  // ab reads done; alias region becomes writable

  // ---- z2 (exact pairwise from LDS), epilogue init ----
  if (tid < QB) {
    z2s[tid] = np_sumsq_256(&zf[tid], QB);
    cnt[tid] = 0;
    ovf[tid] = 0;
  }

  float e2c[8];
#pragma unroll
  for (int nt = 0; nt < 8; ++nt) e2c[nt] = e2[kb + nt * 16 + c];

  float smin[4][4];
#pragma unroll
  for (int mt = 0; mt < 4; ++mt)
#pragma unroll
    for (int r = 0; r < 4; ++r) {
      float m = FLT_MAX_C;
#pragma unroll
      for (int nt = 0; nt < 8; ++nt)
        m = fminf(m, e2c[nt] - 2.0f * acc[mt][nt][r]);
      smin[mt][r] = m;
    }
#pragma unroll
  for (int mt = 0; mt < 4; ++mt)
#pragma unroll
    for (int r = 0; r < 4; ++r) {
#pragma unroll
      for (int m = 1; m < 16; m <<= 1)
        smin[mt][r] = fminf(smin[mt][r], __shfl_xor(smin[mt][r], m, 64));
    }
  if (c == 0) {
#pragma unroll
    for (int mt = 0; mt < 4; ++mt)
#pragma unroll
      for (int r = 0; r < 4; ++r)
        sm[w * QB + mt * 16 + g * 4 + r] = smin[mt][r];
  }
  __syncthreads();
  if (tid < QB) {
    float m = sm[tid];
#pragma unroll
    for (int wv = 1; wv < 8; ++wv) m = fminf(m, sm[wv * QB + tid]);
    qmin[tid] = m;
  }
  __syncthreads();

  // ---- candidate collection ----
#pragma unroll
  for (int mt = 0; mt < 4; ++mt)
#pragma unroll
    for (int r = 0; r < 4; ++r) {
      const int ql = mt * 16 + g * 4 + r;
      const float lim = qmin[ql] + DELTA;
#pragma unroll
      for (int nt = 0; nt < 8; ++nt) {
        float s = e2c[nt] - 2.0f * acc[mt][nt][r];
        if (s <= lim) {
          int p = atomicAdd(&cnt[ql], 1);
          if (p < MAXC) cand[ql * MAXC + p] = kb + nt * 16 + c;
          else ovf[ql] = 1;
        }
      }
    }
  __syncthreads();

  // ---- exact recheck (reference fp32 chain; z from LDS), 8 slots/query ----
  {
    const int q = tid & 63;
    const int slot = tid >> 6;
    const float z2q = z2s[q];
    float bestd = FLT_MAX_C;
    int besti = (1 << 30);
    const bool all = (ovf[q] != 0) || (cnt[q] > MAXC);
    const int count = all ? KCODES : cnt[q];
    for (int ci = slot; ci < count; ci += 8) {
      const int k = all ? ci : cand[q * MAXC + ci];
      const float4* ek = (const float4*)(emb + (size_t)k * DDIM);
      float a0 = 0.f;
      for (int dd = 0; dd < 64; ++dd) {
        float4 e4 = ek[dd];
        a0 = __fmaf_rn(zf[(dd * 4 + 0) * QB + q], e4.x, a0);
        a0 = __fmaf_rn(zf[(dd * 4 + 1) * QB + q], e4.y, a0);
        a0 = __fmaf_rn(zf[(dd * 4 + 2) * QB + q], e4.z, a0);
        a0 = __fmaf_rn(zf[(dd * 4 + 3) * QB + q], e4.w, a0);
      }
      float dist = __fsub_rn(__fadd_rn(z2q, e2[k]), __fmul_rn(2.0f, a0));
      if (dist < bestd || (dist == bestd && k < besti)) { bestd = dist; besti = k; }
    }
    bd[q * 8 + slot] = bestd;
    bk[q * 8 + slot] = besti;
  }
  __syncthreads();

  if (tid < QB) {
    float B = bd[tid * 8 + 0];
    int K = bk[tid * 8 + 0];
#pragma unroll
    for (int s = 1; s < 8; ++s) {
      float d2 = bd[tid * 8 + s];
      int k2 = bk[tid * 8 + s];
      if (d2 < B || (d2 == B && k2 < K)) { B = d2; K = k2; }
    }
    idx[n0 + tid] = K;
    atomicAdd(&hist[K], 1);
    double ls = (double)B;
#pragma unroll
    for (int m = 1; m < 64; m <<= 1) ls += __shfl_xor(ls, m, 64);
    if (tid == 0) lossp[blockIdx.x] = ls;
  }
}

// ---------------------------------------------------------------------------
// k_idxout: indices as FLOAT32
// ---------------------------------------------------------------------------
__global__ void k_idxout(const int* __restrict__ idx,
                         float* __restrict__ oidx) {
  int n = blockIdx.x * 256 + threadIdx.x;
  oidx[n] = (float)(idx[n] & (KCODES - 1));
}

// ---------------------------------------------------------------------------
// k_gather: out[b,d,t] = emb[idx[b,t], d]; one block per (b,d)
// ---------------------------------------------------------------------------
__global__ void k_gather(const float* __restrict__ embT,
                         const int* __restrict__ idx,
                         float* __restrict__ out) {
  __shared__ float er[KCODES];
  const int blk = blockIdx.x;  // b*D + d
  const int bq = blk >> 8;
  const int d = blk & 255;
  const int tid = threadIdx.x;
  *((float4*)&er[tid * 4]) =
      *((const float4*)(embT + (size_t)d * KCODES + tid * 4));
  __syncthreads();
  const int* ip = idx + (size_t)bq * TLEN;
  float* op = out + (size_t)blk * TLEN;
#pragma unroll
  for (int c = 0; c < 16; ++c) {
    int t = c * 256 + tid;
    int kk = ip[t] & (KCODES - 1);
    op[t] = er[kk];
  }
}

// ---------------------------------------------------------------------------
// k_final: loss and perplexity (deterministic fixed-tree reductions)
// lossp: 1024 per-block partials.
// ---------------------------------------------------------------------------
__global__ void k_final(const int* __restrict__ hist,
                        const double* __restrict__ lossp,
                        float* __restrict__ out2) {
  const int tid = threadIdx.x;  // 256
  double ls = 0.0;
  for (int i = 0; i < 4; ++i) ls += lossp[tid * 4 + i];
  float es = 0.f;
  for (int i = tid; i < KCODES; i += 256) {
    float p = (float)hist[i] / 65536.0f;
    es += p * logf(p + 1e-10f);
  }
#pragma unroll
  for (int m = 1; m < 64; m <<= 1) {
    ls += __shfl_xor(ls, m, 64);
    es += __shfl_xor(es, m, 64);
  }
  __shared__ double lw[4];
  __shared__ float ew[4];
  if ((tid & 63) == 0) { lw[tid >> 6] = ls; ew[tid >> 6] = es; }
  __syncthreads();
  if (tid == 0) {
    double lt = lw[0] + lw[1] + lw[2] + lw[3];
    float et = ew[0] + ew[1] + ew[2] + ew[3];
    float loss = 0.25f * (float)(lt / (double)((long long)NQ * DDIM));
    float perp = expf(-et);
    out2[0] = loss;
    out2[1] = perp;
  }
}

// ---------------------------------------------------------------------------
// workspace layout (bytes):
//   embT  : 0        .. 1048576   (D*K floats)
//   e2    : 1048576  .. 1052672   (K floats)
//   idx   : 1052672  .. 1314816   (N ints)
//   hist  : 1314816  .. 1318912   (K ints)        <- memset each launch
//   lossp : 1318912  .. 1327104   (1024 doubles)  <- fully written
//   ebh   : 1327104  .. 1851392   (K*D bf16 hi)
//   ebl   : 1851392  .. 2375680   (K*D bf16 lo)
// total ~2.4 MB
// ---------------------------------------------------------------------------
extern "C" void kernel_launch(void* const* d_in, const int* in_sizes, int n_in,
                              void* d_out, int out_size, void* d_ws, size_t ws_size,
                              hipStream_t stream) {
  const float* z = (const float*)d_in[0];
  const float* emb = (const float*)d_in[1];
  float* out = (float*)d_out;

  char* ws = (char*)d_ws;
  float* embT = (float*)(ws);
  float* e2 = (float*)(ws + 1048576);
  int* idx = (int*)(ws + 1052672);
  int* hist = (int*)(ws + 1314816);
  double* lossp = (double*)(ws + 1318912);
  short* ebh = (short*)(ws + 1327104);
  short* ebl = (short*)(ws + 1851392);

  float* oidx = out + ((size_t)out_size - 2 - NQ);
  float* out2 = out + ((size_t)out_size - 2);

  // allow 128KB dynamic LDS for k_mdist (no-op if already set / unsupported)
  (void)hipFuncSetAttribute((const void*)k_mdist,
                            hipFuncAttributeMaxDynamicSharedMemorySize,
                            131072);

  hipMemsetAsync(hist, 0, KCODES * sizeof(int), stream);

  k_prep<<<KCODES, 256, 0, stream>>>(emb, embT, e2, ebh, ebl);
  k_mdist<<<NQ / QB, 512, 131072, stream>>>(z, emb, ebh, ebl, e2, idx, hist,
                                            lossp);
  k_idxout<<<NQ / 256, 256, 0, stream>>>(idx, oidx);
  k_gather<<<BB * DDIM, 256, 0, stream>>>(embT, idx, out);
  k_final<<<1, 256, 0, stream>>>(hist, lossp, out2);
}